// Round 12
// baseline (9316.419 us; speedup 1.0000x reference)
//
#include <hip/hip_runtime.h>

#define T_STEPS 2048
#define BATCH 8
#define HID 1024

// ws layout:
//   floats [0, 50331648)      x_proj repacked [b][t][gate][j]: ((b*2048+t)*3+g)*1024 + j
//   byte 201326592 (=192MiB): h double buffer, 2 x 4096 u64, each u64 packs the group's
//                             BATCH-PAIR at one j: slot = parity*4096 + group*1024 + j
//                             {hi = h[b0+1][j] clean, lo = h[b0][j] with bit30 = tag}.
//                             production step s -> parity s&1, tagbit(s) = ((s>>1)&1)^1.
//                             |h|<1 (clamped) => real bit30 == 0. ws poison 0xAAAAAAAA has
//                             bit30=0 != tagbit(0)=1, so poison never validates. 64 KiB.
//
// R12-tlp: R11 (3.17 µs/step) runs at OccupancyPercent 12.3 = 1 wave/SIMD — zero TLP;
// W-latency/poll/barrier stalls are fully exposed (VALUBusy 32%). This round buys TLP
// at FIXED total W traffic: G=4 groups x 128 blocks (512 blocks, 2/CU), block owns
// 8 j x 2 batches, wave owns 2 j (wf[3][2][4] = 24 sunk dwordx4/lane, 192 FMA/lane).
// group = bid>>7: same-gb blocks (bids gb+128g = gb mod 8) stay XCD-colocated
// (R9-proven 4-way L2 sharing of W rows, per-XCD distinct set 1.5MB); bid & bid+256
// (same gb, groups g/g+2) pair on one CU reading IDENTICAL W rows. Residency capacity
// 4 blocks/CU (VGPR<=128, 16KB LDS) for 512 blocks = 2x slack. Exchange protocol
// byte-identical to R11. Clean A/B: domain 64->128 + TLP 1->2, all else fixed.
#define XPROJ_F 50331648ull
#define HBUF64_BYTE_OFF 201326592ull

typedef float f32x4 __attribute__((ext_vector_type(4)));

__device__ __forceinline__ float sigmoidf_(float x) {
    return 1.0f / (1.0f + __expf(-x));
}

// Relaxed AGENT-scope atomics lower to global_load/store ... sc1 — they read/
// write the Infinity Cache (the inter-XCD coherence point) with NO L2
// writeback/invalidate. An aligned 8B store is single-copy atomic, so the
// packed {tag|h_even, h_odd} packet is self-validating: no flags, no fences.
__device__ __forceinline__ unsigned long long ld_u64_agent(const unsigned long long* p) {
    return __hip_atomic_load(p, __ATOMIC_RELAXED, __HIP_MEMORY_SCOPE_AGENT);
}
__device__ __forceinline__ void st_u64_agent(unsigned long long* p, unsigned long long v) {
    __hip_atomic_store(p, v, __ATOMIC_RELAXED, __HIP_MEMORY_SCOPE_AGENT);
}

// ---------------- Phase 1: x_proj = x @ W_ih^T + b_ih ----------------
// 128x128 tile, BK=16, 256 threads, 8x8 micro-tile. Epilogue writes the
// [b][t][g][j] layout the scan wants (j-contiguous -> two float4 stores/row).
__global__ __launch_bounds__(256) void gemm_xproj(
        const float* __restrict__ x, const float* __restrict__ Wih,
        const float* __restrict__ bih, float* __restrict__ xproj) {
    __shared__ float a_lds[16][128];  // [k][m]
    __shared__ float b_lds[16][128];  // [k][n]
    const int tid = threadIdx.x;
    const int m0 = blockIdx.x * 128;
    const int n0 = blockIdx.y * 128;
    const int tx = tid & 15, ty = tid >> 4;

    float acc[8][8];
#pragma unroll
    for (int i = 0; i < 8; i++)
#pragma unroll
        for (int jj = 0; jj < 8; jj++) acc[i][jj] = 0.f;

    for (int k0 = 0; k0 < 1024; k0 += 16) {
#pragma unroll
        for (int l = 0; l < 2; l++) {
            const int c = tid + l * 256;
            const int row = c >> 2;
            const int f4 = c & 3;
            float4 av = *reinterpret_cast<const float4*>(
                x + (size_t)(m0 + row) * 1024 + k0 + f4 * 4);
            float4 bv = *reinterpret_cast<const float4*>(
                Wih + (size_t)(n0 + row) * 1024 + k0 + f4 * 4);
            a_lds[f4 * 4 + 0][row] = av.x; a_lds[f4 * 4 + 1][row] = av.y;
            a_lds[f4 * 4 + 2][row] = av.z; a_lds[f4 * 4 + 3][row] = av.w;
            b_lds[f4 * 4 + 0][row] = bv.x; b_lds[f4 * 4 + 1][row] = bv.y;
            b_lds[f4 * 4 + 2][row] = bv.z; b_lds[f4 * 4 + 3][row] = bv.w;
        }
        __syncthreads();
#pragma unroll
        for (int kk = 0; kk < 16; kk++) {
            float a[8], b[8];
            *reinterpret_cast<float4*>(&a[0]) =
                *reinterpret_cast<float4*>(&a_lds[kk][ty * 8]);
            *reinterpret_cast<float4*>(&a[4]) =
                *reinterpret_cast<float4*>(&a_lds[kk][ty * 8 + 4]);
            *reinterpret_cast<float4*>(&b[0]) =
                *reinterpret_cast<float4*>(&b_lds[kk][tx * 8]);
            *reinterpret_cast<float4*>(&b[4]) =
                *reinterpret_cast<float4*>(&b_lds[kk][tx * 8 + 4]);
#pragma unroll
            for (int i = 0; i < 8; i++)
#pragma unroll
                for (int jj = 0; jj < 8; jj++)
                    acc[i][jj] = fmaf(a[i], b[jj], acc[i][jj]);
        }
        __syncthreads();
    }

    float bias[8];
    *reinterpret_cast<float4*>(&bias[0]) =
        *reinterpret_cast<const float4*>(bih + n0 + tx * 8);
    *reinterpret_cast<float4*>(&bias[4]) =
        *reinterpret_cast<const float4*>(bih + n0 + tx * 8 + 4);
    // m = b*T + t; 128-row m-tiles never straddle a batch (T=2048 % 128 == 0).
    // n-tile (128 wide) never straddles a gate (1024 % 128 == 0).
    const int n_base = n0 + tx * 8;
    const int g = n_base >> 10;
    const int j0 = n_base & 1023;
#pragma unroll
    for (int i = 0; i < 8; i++) {
        const int m = m0 + ty * 8 + i;
        const int b = m >> 11;        // m / 2048
        const int t = m & 2047;
        float* dst = xproj + (((size_t)b * 2048 + t) * 3 + g) * 1024 + j0;
        float4 r0 = {acc[i][0] + bias[0], acc[i][1] + bias[1],
                     acc[i][2] + bias[2], acc[i][3] + bias[3]};
        float4 r1 = {acc[i][4] + bias[4], acc[i][5] + bias[5],
                     acc[i][6] + bias[6], acc[i][7] + bias[7]};
        *reinterpret_cast<float4*>(dst) = r0;
        *reinterpret_cast<float4*>(dst + 4) = r1;
    }
}

// ---------------- Phase 2: sequential GRU scan, 2 blocks/CU TLP ----------------
// 512 blocks x 256 threads (4 waves), 2 blocks/CU resident (capacity 4).
// group = bid>>7 (4 groups x 128 blocks) owns batches {2g, 2g+1}; gb = bid&127.
// Same-gb blocks (bids gb+128g, all == gb mod 8) land on ONE XCD -> 4-way W
// sharing in L2 (per-XCD distinct W set = 16 slices x 96KB = 1.5MB, resident).
// Block owns j in [gb*8, gb*8+8); wave w owns the j pair jb_w = gb*8 + w*2 for
// both batches. Lane c = lane&3: bb = lane&1, jj = (lane>>1)&1. Per lane:
// k-chunk {4L+256m+e}; 3 gates x 2 j x 2 b x 16 k = 192 FMA; W = plain
// pre-loop f32x4 loads SUNK into the t-loop (24 in-loop dwordx4/lane from L2,
// compiler-scheduled); hv = 8 conflict-free ds_read_b128.
// Per step: gx prefetch -> 4 packed-tagged u64 poll -> unpack to LDS (dbuf) ->
// sync -> hv/hprev -> matvec -> 21-shuffle fold reduce -> gates ->
// 2 packed u64 + 4 out stores per wave.
__global__ __launch_bounds__(256, 2) void gru_scan(
        const float* __restrict__ Whh, const float* __restrict__ bhh,
        const float* __restrict__ xproj, float* __restrict__ out,
        unsigned long long* __restrict__ hbuf64) {
    __shared__ float hshare[2][2][HID];   // 16 KB, [parity][b_local][j]
    const int tid = threadIdx.x;
    const int bid = blockIdx.x;
    const int wave = tid >> 6;            // 0..3
    const int lane = tid & 63;
    const int group = bid >> 7;           // 4 groups x 128 blocks (XCD-aligned)
    const int gb = bid & 127;             // block within group
    const int b0 = group * 2;             // first of this group's 2 batches
    const int jb_w = gb * 8 + wave * 2;   // wave's j pair (even base)

    const int bb_l = lane & 1;
    const int jj_l = (lane >> 1) & 1;
    const int j_l = jb_w + jj_l;
    const int b_l = b0 + bb_l;

    const float bh0 = bhh[j_l];
    const float bh1 = bhh[1024 + j_l];
    const float bh2 = bhh[2048 + j_l];
    const float CL = 0x1.fffffep-1f;   // largest float < 1: keeps bit30 == 0

    // W fragment, PLAIN loads declared pre-loop: rows g*1024 + (jb_w+jj),
    // lane's contiguous 16-k chunk {4L+256m+e} as f32x4. Live set exceeds the
    // (256,2) 128-VGPR budget beside the working set, so the allocator SINKS
    // these loads into the t-loop (R11-verified: VGPR 128, no spill) — emitted
    // as in-loop global_load_dwordx4 from the XCD-resident L2, freely
    // scheduled. Do NOT volatile/asm-pin (R5/R6 spill; R9 fence serialization).
    f32x4 wf[3][2][4];   // [gate][jj][m]
#pragma unroll
    for (int g = 0; g < 3; g++)
#pragma unroll
        for (int jj = 0; jj < 2; jj++)
#pragma unroll
            for (int m = 0; m < 4; m++)
                wf[g][jj][m] = *reinterpret_cast<const f32x4*>(
                    Whh + (size_t)(g * 1024 + jb_w + jj) * 1024 +
                    4 * lane + 256 * m);

    // ---- t = 0: h_prev = 0 -> g_h = b_hh ----
    {
        const size_t xb = ((size_t)b_l * 2048 + 0) * 3072 + j_l;
        const float r = sigmoidf_(xproj[xb] + bh0);
        const float z = sigmoidf_(xproj[xb + 1024] + bh1);
        const float n = tanhf(xproj[xb + 2048] + r * bh2);
        float hnew = (1.f - z) * n;
        hnew = fminf(fmaxf(hnew, -CL), CL);
        const float hpair = __shfl_xor(hnew, 1);  // partner batch, same j
        const unsigned lo = __float_as_uint(hnew) | (1u << 30);  // tagbit(0)=1
        const unsigned hi = __float_as_uint(hpair);
        if (lane < 4 && (lane & 1) == 0)   // lanes 0,2 -> jj 0,1
            st_u64_agent(hbuf64 + (size_t)group * 1024 + j_l,
                         ((unsigned long long)hi << 32) | lo);
        if (lane < 4)
            out[((size_t)b_l * 2048) * 1024 + j_l] = hnew;
    }

    for (int t = 1; t < T_STEPS; t++) {
        // gx prefetch (cached loads, hidden under the staging/poll)
        const size_t xb = ((size_t)b_l * 2048 + t) * 3072 + j_l;
        const float gxr = xproj[xb];
        const float gxz = xproj[xb + 1024];
        const float gxn = xproj[xb + 2048];

        // ---- stage h(t-1): 4 packed tagged u64 loads per thread ----
        const int par = (t - 1) & 1;
        const unsigned long long* src =
            hbuf64 + (size_t)par * 4096 + (size_t)group * 1024;
        const unsigned expect = (((unsigned)(t - 1) >> 1) & 1u) ^ 1u;
        unsigned long long v[4];
#pragma unroll
        for (int i = 0; i < 4; i++)
            v[i] = ld_u64_agent(src + tid + 256 * i);
        for (;;) {
            unsigned bad = 0;
#pragma unroll
            for (int i = 0; i < 4; i++)
                bad |= (((unsigned)(v[i] >> 30)) & 1u) ^ expect;
            if (bad == 0) break;
            __builtin_amdgcn_s_sleep(1);
#pragma unroll
            for (int i = 0; i < 4; i++)
                if ((((unsigned)(v[i] >> 30)) & 1u) != expect)
                    v[i] = ld_u64_agent(src + tid + 256 * i);
        }
#pragma unroll
        for (int i = 0; i < 4; i++) {
            const int s = tid + 256 * i;    // slot = j
            hshare[par][0][s] = __uint_as_float((unsigned)v[i] & 0xBFFFFFFFu);
            hshare[par][1][s] = __uint_as_float((unsigned)(v[i] >> 32));
        }
        __syncthreads();   // whole block validated + staged h(t-1)
        // (no trailing barrier: next step stages into the other parity half)

        const float hprev = hshare[par][bb_l][j_l];

        // hv held in regs across the matvec: 8 ds_read_b128
        f32x4 hv[2][4];
#pragma unroll
        for (int bb = 0; bb < 2; bb++)
#pragma unroll
            for (int m = 0; m < 4; m++)
                hv[bb][m] = *reinterpret_cast<const f32x4*>(
                    &hshare[par][bb][4 * lane + 256 * m]);

        // ---- matvec: 3 gates x 2 j x 2 b x 16 k = 192 FMA, compiler-scheduled
        // (the sunk wf loads interleave freely with FMAs and the poll above) ----
        float acc[3][4];   // [g][jj*2+bb]
#pragma unroll
        for (int g = 0; g < 3; g++)
#pragma unroll
            for (int q = 0; q < 4; q++) acc[g][q] = 0.f;
#pragma unroll
        for (int jj = 0; jj < 2; jj++)
#pragma unroll
            for (int bb = 0; bb < 2; bb++)
#pragma unroll
                for (int m = 0; m < 4; m++)
#pragma unroll
                    for (int e = 0; e < 4; e++) {
                        acc[0][jj * 2 + bb] = fmaf(wf[0][jj][m][e],
                            hv[bb][m][e], acc[0][jj * 2 + bb]);
                        acc[1][jj * 2 + bb] = fmaf(wf[1][jj][m][e],
                            hv[bb][m][e], acc[1][jj * 2 + bb]);
                        acc[2][jj * 2 + bb] = fmaf(wf[2][jj][m][e],
                            hv[bb][m][e], acc[2][jj * 2 + bb]);
                    }

        // ---- value-folding reduce over the 64-way K split ----
        // fold bb vs lane-bit0, jj vs lane-bit1, then butterflies 4..32;
        // lane l ends with full sums for c = l&3. 21 shuffles total.
        float a2[3][2];
#pragma unroll
        for (int g = 0; g < 3; g++)
#pragma unroll
            for (int k = 0; k < 2; k++) {
                const float e = acc[g][2 * k], o = acc[g][2 * k + 1];
                const float give = (lane & 1) ? e : o;
                const float keep = (lane & 1) ? o : e;
                a2[g][k] = keep + __shfl_xor(give, 1);
            }
        float a1[3];
#pragma unroll
        for (int g = 0; g < 3; g++) {
            const float e = a2[g][0], o = a2[g][1];
            const float give = (lane & 2) ? e : o;
            const float keep = (lane & 2) ? o : e;
            a1[g] = keep + __shfl_xor(give, 2);
        }
#pragma unroll
        for (int m = 4; m <= 32; m <<= 1)
#pragma unroll
            for (int g = 0; g < 3; g++) a1[g] += __shfl_xor(a1[g], m);

        // ---- gates on all lanes (a1 valid for c = lane&3 on every lane) ----
        const float r = sigmoidf_(gxr + a1[0] + bh0);
        const float z = sigmoidf_(gxz + a1[1] + bh1);
        const float n = tanhf(gxn + r * (a1[2] + bh2));
        float hnew = (1.f - z) * n + z * hprev;
        hnew = fminf(fmaxf(hnew, -CL), CL);
        const float hpair = __shfl_xor(hnew, 1);
        const unsigned tagst = (((unsigned)t >> 1) & 1u) ^ 1u;
        const unsigned lo = __float_as_uint(hnew) | (tagst << 30);
        const unsigned hi = __float_as_uint(hpair);
        if (lane < 4 && (lane & 1) == 0)
            st_u64_agent(hbuf64 + (size_t)(t & 1) * 4096 +
                             (size_t)group * 1024 + j_l,
                         ((unsigned long long)hi << 32) | lo);
        if (lane < 4)
            out[((size_t)b_l * 2048 + t) * 1024 + j_l] = hnew;
    }
}

extern "C" void kernel_launch(void* const* d_in, const int* in_sizes, int n_in,
                              void* d_out, int out_size, void* d_ws,
                              size_t ws_size, hipStream_t stream) {
    const float* x    = (const float*)d_in[0];
    const float* Wih  = (const float*)d_in[1];
    const float* bih  = (const float*)d_in[2];
    const float* Whh  = (const float*)d_in[3];
    const float* bhh  = (const float*)d_in[4];
    float* outp = (float*)d_out;

    float* xproj = (float*)d_ws;
    unsigned long long* hbuf64 =
        (unsigned long long*)((char*)d_ws + HBUF64_BYTE_OFF);

    dim3 g1(128, 24);   // M/128, N/128
    gemm_xproj<<<g1, 256, 0, stream>>>(x, Wih, bih, xproj);
    gru_scan<<<512, 256, 0, stream>>>(Whh, bhh, xproj, outp, hbuf64);
}

// Round 13
// 8396.044 us; speedup vs baseline: 1.1096x; 1.1096x over previous
//
#include <hip/hip_runtime.h>

#define T_STEPS 2048
#define BATCH 8
#define HID 1024

// ws layout:
//   floats [0, 50331648)      x_proj repacked [b][t][gate][j]: ((b*2048+t)*3+g)*1024 + j
//   byte 201326592 (=192MiB): h double buffer, 2 x 4096 u64, each u64 packs the group's
//                             BATCH-PAIR at one j: slot = parity*4096 + group*1024 + j
//                             {hi = h[b0+1][j] clean, lo = h[b0][j] with bit30 = tag}.
//                             production step s -> parity s&1, tagbit(s) = ((s>>1)&1)^1.
//                             |h|<1 (clamped) => real bit30 == 0. ws poison 0xAAAAAAAA has
//                             bit30=0 != tagbit(0)=1, so poison never validates. 64 KiB.
//
// R13 = R11 (best: 6.5ms scan, 3.17 µs/step) + W-prefetch-under-poll.
// R12 falsified the TLP lever (occupancy 2x -> VALUBusy frozen at 32%, dur worse):
// waves of a domain stall together, and the 128-block domain pays straggler tax.
// 64-block domains + 1 block/CU stands. R11's residual: compiler-sunk W loads issue
// AFTER the poll+barrier (serialized with the ~0.7µs poll dead-time). This round:
// gate-r's 16 dwordx4 are issued via asm at loop top (un-sinkable), drained by ONE
// vmcnt(0) at poll-exit where they are ~0.7µs old (free wait; R9's mistake was 4
// mid-matvec fence pairs). Gates z,n stay compiler-sunk plain loads. sched_barrier(0)
// after the wait per rule 18. Critical-path L2 W stream drops ~1/3.
#define XPROJ_F 50331648ull
#define HBUF64_BYTE_OFF 201326592ull

typedef float f32x4 __attribute__((ext_vector_type(4)));

__device__ __forceinline__ float sigmoidf_(float x) {
    return 1.0f / (1.0f + __expf(-x));
}

// Relaxed AGENT-scope atomics lower to global_load/store ... sc1 — they read/
// write the Infinity Cache (the inter-XCD coherence point) with NO L2
// writeback/invalidate. An aligned 8B store is single-copy atomic, so the
// packed {tag|h_even, h_odd} packet is self-validating: no flags, no fences.
__device__ __forceinline__ unsigned long long ld_u64_agent(const unsigned long long* p) {
    return __hip_atomic_load(p, __ATOMIC_RELAXED, __HIP_MEMORY_SCOPE_AGENT);
}
__device__ __forceinline__ void st_u64_agent(unsigned long long* p, unsigned long long v) {
    __hip_atomic_store(p, v, __ATOMIC_RELAXED, __HIP_MEMORY_SCOPE_AGENT);
}

// inline-asm W load: issued where written (cannot be sunk to first use), so the
// load flies during the poll dead-time. offset is a 13-bit signed byte imm.
#define LDW(dst, base, off)                                              \
    asm volatile("global_load_dwordx4 %0, %1, off offset:" #off          \
                 : "=v"(dst) : "v"(base) : "memory")

// ---------------- Phase 1: x_proj = x @ W_ih^T + b_ih ----------------
// 128x128 tile, BK=16, 256 threads, 8x8 micro-tile. Epilogue writes the
// [b][t][g][j] layout the scan wants (j-contiguous -> two float4 stores/row).
__global__ __launch_bounds__(256) void gemm_xproj(
        const float* __restrict__ x, const float* __restrict__ Wih,
        const float* __restrict__ bih, float* __restrict__ xproj) {
    __shared__ float a_lds[16][128];  // [k][m]
    __shared__ float b_lds[16][128];  // [k][n]
    const int tid = threadIdx.x;
    const int m0 = blockIdx.x * 128;
    const int n0 = blockIdx.y * 128;
    const int tx = tid & 15, ty = tid >> 4;

    float acc[8][8];
#pragma unroll
    for (int i = 0; i < 8; i++)
#pragma unroll
        for (int jj = 0; jj < 8; jj++) acc[i][jj] = 0.f;

    for (int k0 = 0; k0 < 1024; k0 += 16) {
#pragma unroll
        for (int l = 0; l < 2; l++) {
            const int c = tid + l * 256;
            const int row = c >> 2;
            const int f4 = c & 3;
            float4 av = *reinterpret_cast<const float4*>(
                x + (size_t)(m0 + row) * 1024 + k0 + f4 * 4);
            float4 bv = *reinterpret_cast<const float4*>(
                Wih + (size_t)(n0 + row) * 1024 + k0 + f4 * 4);
            a_lds[f4 * 4 + 0][row] = av.x; a_lds[f4 * 4 + 1][row] = av.y;
            a_lds[f4 * 4 + 2][row] = av.z; a_lds[f4 * 4 + 3][row] = av.w;
            b_lds[f4 * 4 + 0][row] = bv.x; b_lds[f4 * 4 + 1][row] = bv.y;
            b_lds[f4 * 4 + 2][row] = bv.z; b_lds[f4 * 4 + 3][row] = bv.w;
        }
        __syncthreads();
#pragma unroll
        for (int kk = 0; kk < 16; kk++) {
            float a[8], b[8];
            *reinterpret_cast<float4*>(&a[0]) =
                *reinterpret_cast<float4*>(&a_lds[kk][ty * 8]);
            *reinterpret_cast<float4*>(&a[4]) =
                *reinterpret_cast<float4*>(&a_lds[kk][ty * 8 + 4]);
            *reinterpret_cast<float4*>(&b[0]) =
                *reinterpret_cast<float4*>(&b_lds[kk][tx * 8]);
            *reinterpret_cast<float4*>(&b[4]) =
                *reinterpret_cast<float4*>(&b_lds[kk][tx * 8 + 4]);
#pragma unroll
            for (int i = 0; i < 8; i++)
#pragma unroll
                for (int jj = 0; jj < 8; jj++)
                    acc[i][jj] = fmaf(a[i], b[jj], acc[i][jj]);
        }
        __syncthreads();
    }

    float bias[8];
    *reinterpret_cast<float4*>(&bias[0]) =
        *reinterpret_cast<const float4*>(bih + n0 + tx * 8);
    *reinterpret_cast<float4*>(&bias[4]) =
        *reinterpret_cast<const float4*>(bih + n0 + tx * 8 + 4);
    // m = b*T + t; 128-row m-tiles never straddle a batch (T=2048 % 128 == 0).
    // n-tile (128 wide) never straddles a gate (1024 % 128 == 0).
    const int n_base = n0 + tx * 8;
    const int g = n_base >> 10;
    const int j0 = n_base & 1023;
#pragma unroll
    for (int i = 0; i < 8; i++) {
        const int m = m0 + ty * 8 + i;
        const int b = m >> 11;        // m / 2048
        const int t = m & 2047;
        float* dst = xproj + (((size_t)b * 2048 + t) * 3 + g) * 1024 + j0;
        float4 r0 = {acc[i][0] + bias[0], acc[i][1] + bias[1],
                     acc[i][2] + bias[2], acc[i][3] + bias[3]};
        float4 r1 = {acc[i][4] + bias[4], acc[i][5] + bias[5],
                     acc[i][6] + bias[6], acc[i][7] + bias[7]};
        *reinterpret_cast<float4*>(dst) = r0;
        *reinterpret_cast<float4*>(dst + 4) = r1;
    }
}

// ---------------- Phase 2: sequential GRU scan, 64-block XCD-aligned domains ----
// 256 blocks x 256 threads (4 waves). group = bid>>6 (4 groups x 64 blocks) owns
// batches {2g, 2g+1}; gb = bid&63. Same-gb blocks of the 4 groups (bids gb+64g,
// all == gb mod 8) land on ONE XCD -> 4-way W sharing in its L2 (distinct set
// 1.5MB, resident; R9/R11 verified FETCH ~0.5GB). Block owns j in [gb*16,
// gb*16+16); wave w owns 4 j for both batches. Lane c = lane&7: bb = lane&1,
// jj = (lane>>1)&3. Per lane: k-chunk {4L+256m+e}; 384 FMA.
// W: gate-r = 16 asm dwordx4 issued at loop top (fly under the poll, drained
// by one free vmcnt(0) at poll-exit); gates z,n = plain pre-loop loads SUNK
// into the matvec (R11 behavior). hv = 8 conflict-free ds_read_b128.
// Per step: issue W_r -> gx prefetch -> 4 packed-tagged u64 poll -> vmcnt(0)
// + sched_barrier -> unpack to LDS (dbuf) -> sync -> hv/hprev -> matvec ->
// 30-shuffle fold reduce -> gates -> 4 packed u64 + 8 out stores per wave.
__global__ __launch_bounds__(256, 2) void gru_scan(
        const float* __restrict__ Whh, const float* __restrict__ bhh,
        const float* __restrict__ xproj, float* __restrict__ out,
        unsigned long long* __restrict__ hbuf64) {
    __shared__ float hshare[2][2][HID];   // 16 KB, [parity][b_local][j]
    const int tid = threadIdx.x;
    const int bid = blockIdx.x;
    const int wave = tid >> 6;            // 0..3
    const int lane = tid & 63;
    const int group = bid >> 6;           // 4 groups x 64 blocks (XCD-aligned)
    const int gb = bid & 63;              // block within group
    const int b0 = group * 2;             // first of this group's 2 batches
    const int jb_w = gb * 16 + wave * 4;  // wave's first j

    const int bb_l = lane & 1;
    const int jj_l = (lane >> 1) & 3;
    const int j_l = jb_w + jj_l;
    const int b_l = b0 + bb_l;

    const float bh0 = bhh[j_l];
    const float bh1 = bhh[1024 + j_l];
    const float bh2 = bhh[2048 + j_l];
    const float CL = 0x1.fffffep-1f;   // largest float < 1: keeps bit30 == 0

    // gate-r row bases for the asm prefetch (per jj; offsets 0..3072 < 4096)
    const float* wr0 = Whh + (size_t)(jb_w + 0) * 1024 + 4 * lane;
    const float* wr1 = Whh + (size_t)(jb_w + 1) * 1024 + 4 * lane;
    const float* wr2 = Whh + (size_t)(jb_w + 2) * 1024 + 4 * lane;
    const float* wr3 = Whh + (size_t)(jb_w + 3) * 1024 + 4 * lane;

    // Gates z,n: PLAIN loads declared pre-loop; the allocator SINKS them into
    // the t-loop (R11-verified: VGPR 128, no spill) — in-loop dwordx4 from the
    // XCD-resident L2, freely scheduled against the matvec FMAs.
    f32x4 wzn[2][4][4];   // [gate-1][jj][m]
#pragma unroll
    for (int g = 1; g < 3; g++)
#pragma unroll
        for (int jj = 0; jj < 4; jj++)
#pragma unroll
            for (int m = 0; m < 4; m++)
                wzn[g - 1][jj][m] = *reinterpret_cast<const f32x4*>(
                    Whh + (size_t)(g * 1024 + jb_w + jj) * 1024 +
                    4 * lane + 256 * m);

    // ---- t = 0: h_prev = 0 -> g_h = b_hh ----
    {
        const size_t xb = ((size_t)b_l * 2048 + 0) * 3072 + j_l;
        const float r = sigmoidf_(xproj[xb] + bh0);
        const float z = sigmoidf_(xproj[xb + 1024] + bh1);
        const float n = tanhf(xproj[xb + 2048] + r * bh2);
        float hnew = (1.f - z) * n;
        hnew = fminf(fmaxf(hnew, -CL), CL);
        const float hpair = __shfl_xor(hnew, 1);  // partner batch, same j
        const unsigned lo = __float_as_uint(hnew) | (1u << 30);  // tagbit(0)=1
        const unsigned hi = __float_as_uint(hpair);
        if (lane < 8 && (lane & 1) == 0)   // lanes 0,2,4,6 -> jj 0..3
            st_u64_agent(hbuf64 + (size_t)group * 1024 + j_l,
                         ((unsigned long long)hi << 32) | lo);
        if (lane < 8)
            out[((size_t)b_l * 2048) * 1024 + j_l] = hnew;
    }

    for (int t = 1; t < T_STEPS; t++) {
        // ---- gate-r W prefetch: 16 asm dwordx4, in flight during the poll ----
        f32x4 wr[4][4];   // [jj][m]
        LDW(wr[0][0], wr0, 0);    LDW(wr[0][1], wr0, 1024);
        LDW(wr[0][2], wr0, 2048); LDW(wr[0][3], wr0, 3072);
        LDW(wr[1][0], wr1, 0);    LDW(wr[1][1], wr1, 1024);
        LDW(wr[1][2], wr1, 2048); LDW(wr[1][3], wr1, 3072);
        LDW(wr[2][0], wr2, 0);    LDW(wr[2][1], wr2, 1024);
        LDW(wr[2][2], wr2, 2048); LDW(wr[2][3], wr2, 3072);
        LDW(wr[3][0], wr3, 0);    LDW(wr[3][1], wr3, 1024);
        LDW(wr[3][2], wr3, 2048); LDW(wr[3][3], wr3, 3072);

        // gx prefetch (cached loads, hidden under the staging/poll)
        const size_t xb = ((size_t)b_l * 2048 + t) * 3072 + j_l;
        const float gxr = xproj[xb];
        const float gxz = xproj[xb + 1024];
        const float gxn = xproj[xb + 2048];

        // ---- stage h(t-1): 4 packed tagged u64 loads per thread ----
        const int par = (t - 1) & 1;
        const unsigned long long* src =
            hbuf64 + (size_t)par * 4096 + (size_t)group * 1024;
        const unsigned expect = (((unsigned)(t - 1) >> 1) & 1u) ^ 1u;
        unsigned long long v[4];
#pragma unroll
        for (int i = 0; i < 4; i++)
            v[i] = ld_u64_agent(src + tid + 256 * i);
        for (;;) {
            unsigned bad = 0;
#pragma unroll
            for (int i = 0; i < 4; i++)
                bad |= (((unsigned)(v[i] >> 30)) & 1u) ^ expect;
            if (bad == 0) break;
            __builtin_amdgcn_s_sleep(1);
#pragma unroll
            for (int i = 0; i < 4; i++)
                if ((((unsigned)(v[i] >> 30)) & 1u) != expect)
                    v[i] = ld_u64_agent(src + tid + 256 * i);
        }

        // Drain the asm W loads (issued ~a full poll ago -> free wait); the
        // sched_barrier keeps any wr-consuming code below this point (rule 18).
        asm volatile("s_waitcnt vmcnt(0)" ::: "memory");
        __builtin_amdgcn_sched_barrier(0);

#pragma unroll
        for (int i = 0; i < 4; i++) {
            const int s = tid + 256 * i;    // slot = j
            hshare[par][0][s] = __uint_as_float((unsigned)v[i] & 0xBFFFFFFFu);
            hshare[par][1][s] = __uint_as_float((unsigned)(v[i] >> 32));
        }
        __syncthreads();   // whole block validated + staged h(t-1)
        // (no trailing barrier: next step stages into the other parity half)

        const float hprev = hshare[par][bb_l][j_l];

        // hv held in regs across the matvec: 8 ds_read_b128
        f32x4 hv[2][4];
#pragma unroll
        for (int bb = 0; bb < 2; bb++)
#pragma unroll
            for (int m = 0; m < 4; m++)
                hv[bb][m] = *reinterpret_cast<const f32x4*>(
                    &hshare[par][bb][4 * lane + 256 * m]);

        // ---- matvec: 3 gates x 4 j x 2 b x 16 k = 384 FMA ----
        // gate r from the prefetched wr regs; gates z,n from compiler-sunk
        // wzn loads interleaved by the scheduler with the FMAs.
        float acc[3][8];   // [g][jj*2+bb]
#pragma unroll
        for (int g = 0; g < 3; g++)
#pragma unroll
            for (int q = 0; q < 8; q++) acc[g][q] = 0.f;
#pragma unroll
        for (int jj = 0; jj < 4; jj++)
#pragma unroll
            for (int bb = 0; bb < 2; bb++)
#pragma unroll
                for (int m = 0; m < 4; m++)
#pragma unroll
                    for (int e = 0; e < 4; e++) {
                        acc[0][jj * 2 + bb] = fmaf(wr[jj][m][e],
                            hv[bb][m][e], acc[0][jj * 2 + bb]);
                        acc[1][jj * 2 + bb] = fmaf(wzn[0][jj][m][e],
                            hv[bb][m][e], acc[1][jj * 2 + bb]);
                        acc[2][jj * 2 + bb] = fmaf(wzn[1][jj][m][e],
                            hv[bb][m][e], acc[2][jj * 2 + bb]);
                    }

        // ---- value-folding reduce over the 64-way K split ----
        // fold bb vs lane-bit0, jj-bit0 vs lane-bit1, jj-bit1 vs lane-bit2,
        // then butterflies 8/16/32; lane l ends with full sums for c = l&7.
        float a4[3][4];
#pragma unroll
        for (int g = 0; g < 3; g++)
#pragma unroll
            for (int k = 0; k < 4; k++) {
                const float e = acc[g][2 * k], o = acc[g][2 * k + 1];
                const float give = (lane & 1) ? e : o;
                const float keep = (lane & 1) ? o : e;
                a4[g][k] = keep + __shfl_xor(give, 1);
            }
        float a2[3][2];
#pragma unroll
        for (int g = 0; g < 3; g++)
#pragma unroll
            for (int k = 0; k < 2; k++) {
                const float e = a4[g][2 * k], o = a4[g][2 * k + 1];
                const float give = (lane & 2) ? e : o;
                const float keep = (lane & 2) ? o : e;
                a2[g][k] = keep + __shfl_xor(give, 2);
            }
        float a1[3];
#pragma unroll
        for (int g = 0; g < 3; g++) {
            const float e = a2[g][0], o = a2[g][1];
            const float give = (lane & 4) ? e : o;
            const float keep = (lane & 4) ? o : e;
            a1[g] = keep + __shfl_xor(give, 4);
        }
#pragma unroll
        for (int m = 8; m <= 32; m <<= 1)
#pragma unroll
            for (int g = 0; g < 3; g++) a1[g] += __shfl_xor(a1[g], m);

        // ---- gates on all lanes (a1 valid for c = lane&7 on every lane) ----
        const float r = sigmoidf_(gxr + a1[0] + bh0);
        const float z = sigmoidf_(gxz + a1[1] + bh1);
        const float n = tanhf(gxn + r * (a1[2] + bh2));
        float hnew = (1.f - z) * n + z * hprev;
        hnew = fminf(fmaxf(hnew, -CL), CL);
        const float hpair = __shfl_xor(hnew, 1);
        const unsigned tagst = (((unsigned)t >> 1) & 1u) ^ 1u;
        const unsigned lo = __float_as_uint(hnew) | (tagst << 30);
        const unsigned hi = __float_as_uint(hpair);
        if (lane < 8 && (lane & 1) == 0)
            st_u64_agent(hbuf64 + (size_t)(t & 1) * 4096 +
                             (size_t)group * 1024 + j_l,
                         ((unsigned long long)hi << 32) | lo);
        if (lane < 8)
            out[((size_t)b_l * 2048 + t) * 1024 + j_l] = hnew;
    }
}

extern "C" void kernel_launch(void* const* d_in, const int* in_sizes, int n_in,
                              void* d_out, int out_size, void* d_ws,
                              size_t ws_size, hipStream_t stream) {
    const float* x    = (const float*)d_in[0];
    const float* Wih  = (const float*)d_in[1];
    const float* bih  = (const float*)d_in[2];
    const float* Whh  = (const float*)d_in[3];
    const float* bhh  = (const float*)d_in[4];
    float* outp = (float*)d_out;

    float* xproj = (float*)d_ws;
    unsigned long long* hbuf64 =
        (unsigned long long*)((char*)d_ws + HBUF64_BYTE_OFF);

    dim3 g1(128, 24);   // M/128, N/128
    gemm_xproj<<<g1, 256, 0, stream>>>(x, Wih, bih, xproj);
    gru_scan<<<256, 256, 0, stream>>>(Whh, bhh, xproj, outp, hbuf64);
}

// Round 14
// 7324.289 us; speedup vs baseline: 1.2720x; 1.1463x over previous
//
#include <hip/hip_runtime.h>

#define T_STEPS 2048
#define BATCH 8
#define HID 1024

// ws layout:
//   floats [0, 50331648)      x_proj repacked [b][t][gate][j]: ((b*2048+t)*3+g)*1024 + j
//   byte 201326592 (=192MiB): h double buffer, 2 x 4096 u64, each u64 packs the group's
//                             BATCH-PAIR at one j: slot = parity*4096 + group*1024 + j
//                             {hi = h[b0+1][j] clean, lo = h[b0][j] with bit30 = tag}.
//                             production step s -> parity s&1, tagbit(s) = ((s>>1)&1)^1.
//                             |h|<1 (clamped) => real bit30 == 0. ws poison 0xAAAAAAAA has
//                             bit30=0 != tagbit(0)=1, so poison never validates. 64 KiB.
//
// R14 = R11 (best: 6.5ms scan) + gate-n W cached in LDS. R13's asm prefetch REGRESSED
// (7.42ms): vmcnt retires in-order, so W loads issued before the poll's tag loads put
// the whole W stream ON the poll's critical path — reverted. The remaining dominant
// term in R11's 3.17µs step is the per-step W stream: 192KB/CU from L2, all 32 CUs of
// an XCD in lockstep -> 6.1MB/step vs ~4.3TB/s per-XCD L2 = ~1.4µs (45%). R12's null
// TLP result corroborates (same demand, 2x occupancy, no gain = BW-bound not
// latency-bound). Fix: gate-n's 64KB W slice -> LDS once (coalesced fill), per-step
// L2 demand 192->128 KB/CU. Total LDS 80KB keeps 2-blocks/CU capacity (slack
// preserved; NOT the R3/R4 zero-slack shape). Gates r,z stay compiler-sunk plain
// loads (R11's proven mechanism).
#define XPROJ_F 50331648ull
#define HBUF64_BYTE_OFF 201326592ull

typedef float f32x4 __attribute__((ext_vector_type(4)));

__device__ __forceinline__ float sigmoidf_(float x) {
    return 1.0f / (1.0f + __expf(-x));
}

// Relaxed AGENT-scope atomics lower to global_load/store ... sc1 — they read/
// write the Infinity Cache (the inter-XCD coherence point) with NO L2
// writeback/invalidate. An aligned 8B store is single-copy atomic, so the
// packed {tag|h_even, h_odd} packet is self-validating: no flags, no fences.
__device__ __forceinline__ unsigned long long ld_u64_agent(const unsigned long long* p) {
    return __hip_atomic_load(p, __ATOMIC_RELAXED, __HIP_MEMORY_SCOPE_AGENT);
}
__device__ __forceinline__ void st_u64_agent(unsigned long long* p, unsigned long long v) {
    __hip_atomic_store(p, v, __ATOMIC_RELAXED, __HIP_MEMORY_SCOPE_AGENT);
}

// ---------------- Phase 1: x_proj = x @ W_ih^T + b_ih ----------------
// 128x128 tile, BK=16, 256 threads, 8x8 micro-tile. Epilogue writes the
// [b][t][g][j] layout the scan wants (j-contiguous -> two float4 stores/row).
__global__ __launch_bounds__(256) void gemm_xproj(
        const float* __restrict__ x, const float* __restrict__ Wih,
        const float* __restrict__ bih, float* __restrict__ xproj) {
    __shared__ float a_lds[16][128];  // [k][m]
    __shared__ float b_lds[16][128];  // [k][n]
    const int tid = threadIdx.x;
    const int m0 = blockIdx.x * 128;
    const int n0 = blockIdx.y * 128;
    const int tx = tid & 15, ty = tid >> 4;

    float acc[8][8];
#pragma unroll
    for (int i = 0; i < 8; i++)
#pragma unroll
        for (int jj = 0; jj < 8; jj++) acc[i][jj] = 0.f;

    for (int k0 = 0; k0 < 1024; k0 += 16) {
#pragma unroll
        for (int l = 0; l < 2; l++) {
            const int c = tid + l * 256;
            const int row = c >> 2;
            const int f4 = c & 3;
            float4 av = *reinterpret_cast<const float4*>(
                x + (size_t)(m0 + row) * 1024 + k0 + f4 * 4);
            float4 bv = *reinterpret_cast<const float4*>(
                Wih + (size_t)(n0 + row) * 1024 + k0 + f4 * 4);
            a_lds[f4 * 4 + 0][row] = av.x; a_lds[f4 * 4 + 1][row] = av.y;
            a_lds[f4 * 4 + 2][row] = av.z; a_lds[f4 * 4 + 3][row] = av.w;
            b_lds[f4 * 4 + 0][row] = bv.x; b_lds[f4 * 4 + 1][row] = bv.y;
            b_lds[f4 * 4 + 2][row] = bv.z; b_lds[f4 * 4 + 3][row] = bv.w;
        }
        __syncthreads();
#pragma unroll
        for (int kk = 0; kk < 16; kk++) {
            float a[8], b[8];
            *reinterpret_cast<float4*>(&a[0]) =
                *reinterpret_cast<float4*>(&a_lds[kk][ty * 8]);
            *reinterpret_cast<float4*>(&a[4]) =
                *reinterpret_cast<float4*>(&a_lds[kk][ty * 8 + 4]);
            *reinterpret_cast<float4*>(&b[0]) =
                *reinterpret_cast<float4*>(&b_lds[kk][tx * 8]);
            *reinterpret_cast<float4*>(&b[4]) =
                *reinterpret_cast<float4*>(&b_lds[kk][tx * 8 + 4]);
#pragma unroll
            for (int i = 0; i < 8; i++)
#pragma unroll
                for (int jj = 0; jj < 8; jj++)
                    acc[i][jj] = fmaf(a[i], b[jj], acc[i][jj]);
        }
        __syncthreads();
    }

    float bias[8];
    *reinterpret_cast<float4*>(&bias[0]) =
        *reinterpret_cast<const float4*>(bih + n0 + tx * 8);
    *reinterpret_cast<float4*>(&bias[4]) =
        *reinterpret_cast<const float4*>(bih + n0 + tx * 8 + 4);
    // m = b*T + t; 128-row m-tiles never straddle a batch (T=2048 % 128 == 0).
    // n-tile (128 wide) never straddles a gate (1024 % 128 == 0).
    const int n_base = n0 + tx * 8;
    const int g = n_base >> 10;
    const int j0 = n_base & 1023;
#pragma unroll
    for (int i = 0; i < 8; i++) {
        const int m = m0 + ty * 8 + i;
        const int b = m >> 11;        // m / 2048
        const int t = m & 2047;
        float* dst = xproj + (((size_t)b * 2048 + t) * 3 + g) * 1024 + j0;
        float4 r0 = {acc[i][0] + bias[0], acc[i][1] + bias[1],
                     acc[i][2] + bias[2], acc[i][3] + bias[3]};
        float4 r1 = {acc[i][4] + bias[4], acc[i][5] + bias[5],
                     acc[i][6] + bias[6], acc[i][7] + bias[7]};
        *reinterpret_cast<float4*>(dst) = r0;
        *reinterpret_cast<float4*>(dst + 4) = r1;
    }
}

// ---------------- Phase 2: sequential GRU scan, 64-block XCD-aligned domains ----
// 256 blocks x 256 threads (4 waves). group = bid>>6 (4 groups x 64 blocks) owns
// batches {2g, 2g+1}; gb = bid&63. Same-gb blocks of the 4 groups (bids gb+64g,
// all == gb mod 8) land on ONE XCD -> 4-way W sharing in its L2 (distinct set
// 1.5MB, resident; R9/R11 verified FETCH ~0.5GB). Block owns j in [gb*16,
// gb*16+16); wave w owns 4 j for both batches. Lane c = lane&7: bb = lane&1,
// jj = (lane>>1)&3. Per lane: k-chunk {4L+256m+e}; 384 FMA.
// W: gate-n's 16 rows (64KB) cached in LDS once (coalesced fill); gates r,z =
// plain pre-loop loads SUNK into the t-loop (R11-proven). hv = 8 conflict-free
// ds_read_b128; gate-n = 16 conflict-free ds_read_b128 (same stride-16B
// pattern as hv). Per-step L2 W demand 192 -> 128 KB/CU.
// Per step: gx prefetch -> 4 packed-tagged u64 poll -> unpack to LDS (dbuf) ->
// sync -> hv/hprev -> matvec -> 30-shuffle fold reduce -> gates ->
// 4 packed u64 + 8 out stores per wave.
__global__ __launch_bounds__(256, 2) void gru_scan(
        const float* __restrict__ Whh, const float* __restrict__ bhh,
        const float* __restrict__ xproj, float* __restrict__ out,
        unsigned long long* __restrict__ hbuf64) {
    __shared__ float hshare[2][2][HID];   // 16 KB, [parity][b_local][j]
    __shared__ float wn_lds[16 * HID];    // 64 KB, gate-n W rows [jr][k]
    const int tid = threadIdx.x;
    const int bid = blockIdx.x;
    const int wave = tid >> 6;            // 0..3
    const int lane = tid & 63;
    const int group = bid >> 6;           // 4 groups x 64 blocks (XCD-aligned)
    const int gb = bid & 63;              // block within group
    const int b0 = group * 2;             // first of this group's 2 batches
    const int jb_w = gb * 16 + wave * 4;  // wave's first j

    const int bb_l = lane & 1;
    const int jj_l = (lane >> 1) & 3;
    const int j_l = jb_w + jj_l;
    const int b_l = b0 + bb_l;

    const float bh0 = bhh[j_l];
    const float bh1 = bhh[1024 + j_l];
    const float bh2 = bhh[2048 + j_l];
    const float CL = 0x1.fffffep-1f;   // largest float < 1: keeps bit30 == 0

    // ---- one-time fill: gate-n W slice (rows 2048 + gb*16 .. +16) -> LDS ----
    // f4 index idx = tid + 256*i: row = idx>>8 (256 f4/row), col4 = idx&255.
    // Consecutive tid -> consecutive col4 of one row: coalesced global reads,
    // conflict-free LDS writes.
#pragma unroll
    for (int i = 0; i < 16; i++) {
        const int idx = tid + 256 * i;
        const int row = idx >> 8;
        const int c4 = idx & 255;
        *reinterpret_cast<f32x4*>(&wn_lds[row * 1024 + 4 * c4]) =
            *reinterpret_cast<const f32x4*>(
                Whh + (size_t)(2 * 1024 + gb * 16 + row) * 1024 + 4 * c4);
    }

    // Gates r,z: PLAIN loads declared pre-loop; the allocator SINKS them into
    // the t-loop (R11-verified: VGPR 128, no spill) — in-loop dwordx4 from the
    // XCD-resident L2, freely scheduled against the matvec FMAs.
    f32x4 wrz[2][4][4];   // [gate][jj][m]
#pragma unroll
    for (int g = 0; g < 2; g++)
#pragma unroll
        for (int jj = 0; jj < 4; jj++)
#pragma unroll
            for (int m = 0; m < 4; m++)
                wrz[g][jj][m] = *reinterpret_cast<const f32x4*>(
                    Whh + (size_t)(g * 1024 + jb_w + jj) * 1024 +
                    4 * lane + 256 * m);

    __syncthreads();   // wn_lds fill visible to all waves

    // ---- t = 0: h_prev = 0 -> g_h = b_hh ----
    {
        const size_t xb = ((size_t)b_l * 2048 + 0) * 3072 + j_l;
        const float r = sigmoidf_(xproj[xb] + bh0);
        const float z = sigmoidf_(xproj[xb + 1024] + bh1);
        const float n = tanhf(xproj[xb + 2048] + r * bh2);
        float hnew = (1.f - z) * n;
        hnew = fminf(fmaxf(hnew, -CL), CL);
        const float hpair = __shfl_xor(hnew, 1);  // partner batch, same j
        const unsigned lo = __float_as_uint(hnew) | (1u << 30);  // tagbit(0)=1
        const unsigned hi = __float_as_uint(hpair);
        if (lane < 8 && (lane & 1) == 0)   // lanes 0,2,4,6 -> jj 0..3
            st_u64_agent(hbuf64 + (size_t)group * 1024 + j_l,
                         ((unsigned long long)hi << 32) | lo);
        if (lane < 8)
            out[((size_t)b_l * 2048) * 1024 + j_l] = hnew;
    }

    for (int t = 1; t < T_STEPS; t++) {
        // gx prefetch (cached loads, hidden under the staging/poll)
        const size_t xb = ((size_t)b_l * 2048 + t) * 3072 + j_l;
        const float gxr = xproj[xb];
        const float gxz = xproj[xb + 1024];
        const float gxn = xproj[xb + 2048];

        // ---- stage h(t-1): 4 packed tagged u64 loads per thread ----
        const int par = (t - 1) & 1;
        const unsigned long long* src =
            hbuf64 + (size_t)par * 4096 + (size_t)group * 1024;
        const unsigned expect = (((unsigned)(t - 1) >> 1) & 1u) ^ 1u;
        unsigned long long v[4];
#pragma unroll
        for (int i = 0; i < 4; i++)
            v[i] = ld_u64_agent(src + tid + 256 * i);
        for (;;) {
            unsigned bad = 0;
#pragma unroll
            for (int i = 0; i < 4; i++)
                bad |= (((unsigned)(v[i] >> 30)) & 1u) ^ expect;
            if (bad == 0) break;
            __builtin_amdgcn_s_sleep(1);
#pragma unroll
            for (int i = 0; i < 4; i++)
                if ((((unsigned)(v[i] >> 30)) & 1u) != expect)
                    v[i] = ld_u64_agent(src + tid + 256 * i);
        }
#pragma unroll
        for (int i = 0; i < 4; i++) {
            const int s = tid + 256 * i;    // slot = j
            hshare[par][0][s] = __uint_as_float((unsigned)v[i] & 0xBFFFFFFFu);
            hshare[par][1][s] = __uint_as_float((unsigned)(v[i] >> 32));
        }
        __syncthreads();   // whole block validated + staged h(t-1)
        // (no trailing barrier: next step stages into the other parity half)

        const float hprev = hshare[par][bb_l][j_l];

        // hv held in regs across the matvec: 8 ds_read_b128
        f32x4 hv[2][4];
#pragma unroll
        for (int bb = 0; bb < 2; bb++)
#pragma unroll
            for (int m = 0; m < 4; m++)
                hv[bb][m] = *reinterpret_cast<const f32x4*>(
                    &hshare[par][bb][4 * lane + 256 * m]);

        // ---- matvec: 3 gates x 4 j x 2 b x 16 k = 384 FMA ----
        // gates r,z from compiler-sunk wrz loads (L2); gate n from LDS
        // (16 b128 reads, same conflict-free stride-16B pattern as hv).
        float acc[3][8];   // [g][jj*2+bb]
#pragma unroll
        for (int g = 0; g < 3; g++)
#pragma unroll
            for (int q = 0; q < 8; q++) acc[g][q] = 0.f;
#pragma unroll
        for (int jj = 0; jj < 4; jj++) {
            const int jr = wave * 4 + jj;   // block-local gate-n row
#pragma unroll
            for (int m = 0; m < 4; m++) {
                const f32x4 wn = *reinterpret_cast<const f32x4*>(
                    &wn_lds[jr * 1024 + 4 * lane + 256 * m]);
#pragma unroll
                for (int bb = 0; bb < 2; bb++)
#pragma unroll
                    for (int e = 0; e < 4; e++) {
                        acc[0][jj * 2 + bb] = fmaf(wrz[0][jj][m][e],
                            hv[bb][m][e], acc[0][jj * 2 + bb]);
                        acc[1][jj * 2 + bb] = fmaf(wrz[1][jj][m][e],
                            hv[bb][m][e], acc[1][jj * 2 + bb]);
                        acc[2][jj * 2 + bb] = fmaf(wn[e],
                            hv[bb][m][e], acc[2][jj * 2 + bb]);
                    }
            }
        }

        // ---- value-folding reduce over the 64-way K split ----
        // fold bb vs lane-bit0, jj-bit0 vs lane-bit1, jj-bit1 vs lane-bit2,
        // then butterflies 8/16/32; lane l ends with full sums for c = l&7.
        float a4[3][4];
#pragma unroll
        for (int g = 0; g < 3; g++)
#pragma unroll
            for (int k = 0; k < 4; k++) {
                const float e = acc[g][2 * k], o = acc[g][2 * k + 1];
                const float give = (lane & 1) ? e : o;
                const float keep = (lane & 1) ? o : e;
                a4[g][k] = keep + __shfl_xor(give, 1);
            }
        float a2[3][2];
#pragma unroll
        for (int g = 0; g < 3; g++)
#pragma unroll
            for (int k = 0; k < 2; k++) {
                const float e = a4[g][2 * k], o = a4[g][2 * k + 1];
                const float give = (lane & 2) ? e : o;
                const float keep = (lane & 2) ? o : e;
                a2[g][k] = keep + __shfl_xor(give, 2);
            }
        float a1[3];
#pragma unroll
        for (int g = 0; g < 3; g++) {
            const float e = a2[g][0], o = a2[g][1];
            const float give = (lane & 4) ? e : o;
            const float keep = (lane & 4) ? o : e;
            a1[g] = keep + __shfl_xor(give, 4);
        }
#pragma unroll
        for (int m = 8; m <= 32; m <<= 1)
#pragma unroll
            for (int g = 0; g < 3; g++) a1[g] += __shfl_xor(a1[g], m);

        // ---- gates on all lanes (a1 valid for c = lane&7 on every lane) ----
        const float r = sigmoidf_(gxr + a1[0] + bh0);
        const float z = sigmoidf_(gxz + a1[1] + bh1);
        const float n = tanhf(gxn + r * (a1[2] + bh2));
        float hnew = (1.f - z) * n + z * hprev;
        hnew = fminf(fmaxf(hnew, -CL), CL);
        const float hpair = __shfl_xor(hnew, 1);
        const unsigned tagst = (((unsigned)t >> 1) & 1u) ^ 1u;
        const unsigned lo = __float_as_uint(hnew) | (tagst << 30);
        const unsigned hi = __float_as_uint(hpair);
        if (lane < 8 && (lane & 1) == 0)
            st_u64_agent(hbuf64 + (size_t)(t & 1) * 4096 +
                             (size_t)group * 1024 + j_l,
                         ((unsigned long long)hi << 32) | lo);
        if (lane < 8)
            out[((size_t)b_l * 2048 + t) * 1024 + j_l] = hnew;
    }
}

extern "C" void kernel_launch(void* const* d_in, const int* in_sizes, int n_in,
                              void* d_out, int out_size, void* d_ws,
                              size_t ws_size, hipStream_t stream) {
    const float* x    = (const float*)d_in[0];
    const float* Wih  = (const float*)d_in[1];
    const float* bih  = (const float*)d_in[2];
    const float* Whh  = (const float*)d_in[3];
    const float* bhh  = (const float*)d_in[4];
    float* outp = (float*)d_out;

    float* xproj = (float*)d_ws;
    unsigned long long* hbuf64 =
        (unsigned long long*)((char*)d_ws + HBUF64_BYTE_OFF);

    dim3 g1(128, 24);   // M/128, N/128
    gemm_xproj<<<g1, 256, 0, stream>>>(x, Wih, bih, xproj);
    gru_scan<<<256, 256, 0, stream>>>(Whh, bhh, xproj, outp, hbuf64);
}